// Round 10
// baseline (140.800 us; speedup 1.0000x reference)
//
#include <hip/hip_runtime.h>
#include <stdint.h>

typedef unsigned short ushort_t;
typedef __bf16 bf16x8 __attribute__((ext_vector_type(8)));
typedef float f32x4 __attribute__((ext_vector_type(4)));
typedef unsigned int u32;

// ---------- bf16 helpers (manual, RNE) ----------
__device__ __forceinline__ float bf2f(ushort_t u) {
    union { u32 u; float f; } x; x.u = ((u32)u) << 16; return x.f;
}
__device__ __forceinline__ ushort_t f2bf(float f) {
    union { float f; u32 u; } x; x.f = f;
    u32 r = x.u + 0x7FFFu + ((x.u >> 16) & 1u);
    return (ushort_t)(r >> 16);
}

// ---------- async global->LDS, 16B per lane ----------
__device__ __forceinline__ void async16(const void* gp, void* lp) {
    __builtin_amdgcn_global_load_lds(
        (const __attribute__((address_space(1))) u32*)(gp),
        (__attribute__((address_space(3))) u32*)(lp),
        16, 0, 0);
}

template<int N>
__device__ __forceinline__ void wait_barrier() {
    asm volatile("s_waitcnt vmcnt(%0)\n\ts_barrier" :: "n"(N) : "memory");
}

// ---------- fused fp32 -> bf16 casts + bias concat (one launch) ----------
__global__ __launch_bounds__(256) void cast_all_kernel(
    const float* __restrict__ hs, const float* __restrict__ Wq,
    const float* __restrict__ Wk, const float* __restrict__ Wv,
    const float* __restrict__ Wo, const float* __restrict__ Rm,
    const float* __restrict__ bq, const float* __restrict__ bk,
    const float* __restrict__ bv,
    ushort_t* __restrict__ Xb, ushort_t* __restrict__ Wcat,
    ushort_t* __restrict__ Wo16, ushort_t* __restrict__ Rbf,
    float* __restrict__ bcat)
{
    int bid = blockIdx.x;
    if (bid == 10244) {   // concatenated qkv bias
        for (int i = threadIdx.x; i < 4096; i += 256) {
            float v = (i < 2048) ? bq[i] : (i < 3072) ? bk[i - 2048] : bv[i - 3072];
            bcat[i] = v;
        }
        return;
    }
    const float* src; ushort_t* dst; int base;
    if (bid < 4096)       { src = hs; dst = Xb;              base = bid; }
    else if (bid < 6144)  { src = Wq; dst = Wcat;            base = bid - 4096; }
    else if (bid < 7168)  { src = Wk; dst = Wcat + 4194304;  base = bid - 6144; }
    else if (bid < 8192)  { src = Wv; dst = Wcat + 6291456;  base = bid - 7168; }
    else if (bid < 10240) { src = Wo; dst = Wo16;            base = bid - 8192; }
    else                  { src = Rm; dst = Rbf;             base = bid - 10240; }
    int i = base * 2048 + threadIdx.x * 8;
    float4 v0 = *reinterpret_cast<const float4*>(src + i);
    float4 v1 = *reinterpret_cast<const float4*>(src + i + 4);
    ushort_t o[8];
    o[0] = f2bf(v0.x); o[1] = f2bf(v0.y); o[2] = f2bf(v0.z); o[3] = f2bf(v0.w);
    o[4] = f2bf(v1.x); o[5] = f2bf(v1.y); o[6] = f2bf(v1.z); o[7] = f2bf(v1.w);
    *reinterpret_cast<uint4*>(dst + i) = *reinterpret_cast<const uint4*>(o);
}

// ============ 8-phase reg-pipelined BMx256 GEMM (R10) ============
// Same tile geometry / stage slots / VM ledger as R7 (verified), but each
// phase issues the NEXT phase's ds_reads into the alternate regset and runs
// MFMA on registers read last phase. Compiler emits counted lgkmcnt before
// each MFMA cluster (waits only for the regs it consumes), so ds_read
// latency hides under the previous MFMA cluster. Boundary phases p0/p4
// (first phase per buffer) read their own data (read-ahead cannot cross
// the VM close). sched_barrier(0) pins reads+stage before the MFMA cluster.
// Victim audit (stage >= 1 barrier after victim's last read-drain) redone
// for shifted read times: all slots safe. VM(2)@p3/p7, VM(0) at final p3.
#define CLOSE_PLAIN __builtin_amdgcn_s_barrier()
#define CLOSE_VM(nn) do { asm volatile("s_waitcnt vmcnt(%0)" :: "n"(nn) : "memory"); \
                          __builtin_amdgcn_s_barrier(); } while (0)
#define SBAR __builtin_amdgcn_sched_barrier(0)

template<int BM, int MBLK, int NBLK, int KC, bool STORE_BF16>
__global__ __launch_bounds__(512, 2) void gemm8r_kernel(
    const ushort_t* __restrict__ A, const ushort_t* __restrict__ B,
    const float* __restrict__ bias, void* __restrict__ C,
    const int M, const int N)
{
    constexpr int NT  = KC / 64;
    constexpr int NI  = NT / 2;
    constexpr int MF2 = BM / 64;       // A frags per half-phase
    constexpr int NFR = BM / 32;
    constexpr int AH  = BM * 64;
    constexpr int SH  = BM / 128;
    constexpr int BUF = 2 * AH + 32768;
    constexpr int TI  = 2 * SH + 4;
    static_assert(NT % 2 == 0 && NI >= 3, "need even NT >= 6");
    __shared__ alignas(16) char lds[2 * BUF];

    const int tid  = threadIdx.x;
    const int wid  = tid >> 6;
    const int lane = tid & 63;
    const int wm = wid >> 2, wn = wid & 3;

    constexpr int XN  = NBLK / 8;
    constexpr int NXR = 8 / XN;
    constexpr int RH  = MBLK / NXR;
    const int x  = blockIdx.x & 7;
    const int kb = blockIdx.x >> 3;
    const int mb = (x % NXR) * RH + (kb >> 3);
    const int nb = (x / NXR) * 8 + (kb & 7);
    const int am0 = mb * BM, bn0 = nb * 256;

    const int sr3 = tid >> 3;
    const int c8  = tid & 7;
    const int cs  = c8 ^ (sr3 & 7);
    const long K2 = (long)KC * 2;
    const char* agp = (const char*)A + (size_t)(am0 + sr3) * K2 + cs * 16;
    const char* bgp = (const char*)B + (size_t)(bn0 + sr3) * K2 + cs * 16;
    const int ldsw = wid << 10;

    const int fr = lane & 15, fc = lane >> 4;
    const int sw0 = ((fc)     ^ (fr & 7)) * 16;
    const int sw1 = ((4 + fc) ^ (fr & 7)) * 16;
    const int abase = wm * AH + fr * 128;
    const int bbase = 2 * AH + wn * 8192 + fr * 128;

    f32x4 acc[NFR][4] = {};
    bf16x8 afX[MF2], afY[MF2], bfX[4], bfY[4];

    auto stage_half = [&](const char* gp, int rowoff, int bufb, int off,
                          long kof, int niss) {
        char* lp = lds + bufb + off + ldsw;
        const char* g = gp + (size_t)rowoff * K2 + kof;
#pragma unroll
        for (int i = 0; i < niss; ++i)
            async16(g + (size_t)(i * 64) * K2, lp + i * 8192);
    };
#define SA0(T) stage_half(agp, 0,      ((T) & 1) * BUF, 0,          (long)(T) * 128, SH)
#define SA1(T) stage_half(agp, BM / 2, ((T) & 1) * BUF, AH,         (long)(T) * 128, SH)
#define SB0(T) stage_half(bgp, 0,      ((T) & 1) * BUF, 2 * AH,     (long)(T) * 128, 2)
#define SB1(T) stage_half(bgp, 128,    ((T) & 1) * BUF, 2 * AH + 16384, (long)(T) * 128, 2)

    auto rdA = [&](bf16x8 (&dst)[MF2], int bufb, int h, int kc) {
        const char* lp_ = lds + bufb;
        const int sw_ = kc ? sw1 : sw0;
#pragma unroll
        for (int j = 0; j < MF2; ++j)
            dst[j] = *(const bf16x8*)(lp_ + abase + (h * MF2 + j) * 2048 + sw_);
    };
    auto rdB = [&](bf16x8 (&dst)[4], int bufb, int kc) {
        const char* lp_ = lds + bufb;
        const int sw_ = kc ? sw1 : sw0;
#pragma unroll
        for (int n = 0; n < 4; ++n)
            dst[n] = *(const bf16x8*)(lp_ + bbase + n * 2048 + sw_);
    };
    auto domf = [&](bf16x8 (&af)[MF2], bf16x8 (&bf)[4], int h) {
        __builtin_amdgcn_s_setprio(1);
#pragma unroll
        for (int j = 0; j < MF2; ++j)
#pragma unroll
            for (int n = 0; n < 4; ++n)
                acc[h * MF2 + j][n] = __builtin_amdgcn_mfma_f32_16x16x32_bf16(
                    af[j], bf[n], acc[h * MF2 + j][n], 0, 0, 0);
        __builtin_amdgcn_s_setprio(0);
    };

// One K-tile = 4 phases on buffer b. Phase p reads regs for p+1; MFMA uses
// regs read at p-1 (p0 is boundary: reads own + p1's).
#define QT(b, S0, C0, S1, C1, S2, C2, S3, C3) do {                 \
    rdA(afX, b, 0, 0); rdB(bfX, b, 0); rdA(afY, b, 1, 0);          \
    S0; SBAR; domf(afX, bfX, 0); C0;                               \
    rdA(afX, b, 0, 1); rdB(bfY, b, 1);                             \
    S1; SBAR; domf(afY, bfX, 1); C1;                               \
    rdA(afY, b, 1, 1);                                             \
    S2; SBAR; domf(afX, bfY, 0); C2;                               \
    S3; SBAR; domf(afY, bfY, 1); C3;                               \
} while (0)

    // prologue: tiles 0 and 1 fully staged; wait until tile 0 landed
    SA0(0); SA1(0); SB0(0); SB1(0);
    SA0(1); SA1(1); SB0(1); SB1(1);
    wait_barrier<TI>();

    // iter 0 (tiles 0,1): p0-p2 stage nothing (tile 1 staged in prologue)
    QT(0,   (void)0, CLOSE_PLAIN, (void)0, CLOSE_PLAIN,
            (void)0, CLOSE_PLAIN, SB0(2),  CLOSE_VM(2));
    QT(BUF, SB1(2),  CLOSE_PLAIN, SA0(2),  CLOSE_PLAIN,
            SA1(2),  CLOSE_PLAIN, SB0(3),  CLOSE_VM(2));

    // steady iters
    for (int i = 1; i <= NI - 2; ++i) {
        const int t = 2 * i;
        QT(0,   SB1(t + 1), CLOSE_PLAIN, SA0(t + 1), CLOSE_PLAIN,
                SA1(t + 1), CLOSE_PLAIN, SB0(t + 2), CLOSE_VM(2));
        QT(BUF, SB1(t + 2), CLOSE_PLAIN, SA0(t + 2), CLOSE_PLAIN,
                SA1(t + 2), CLOSE_PLAIN, SB0(t + 3), CLOSE_VM(2));
    }

    // final iter (tiles NT-2, NT-1)
    {
        constexpr int T1 = NT - 1;
        QT(0,   SB1(T1), CLOSE_PLAIN, SA0(T1), CLOSE_PLAIN,
                SA1(T1), CLOSE_PLAIN, (void)0, CLOSE_VM(0));
        QT(BUF, (void)0, CLOSE_PLAIN, (void)0, CLOSE_PLAIN,
                (void)0, CLOSE_PLAIN, (void)0, CLOSE_PLAIN);
    }

    // epilogue: C/D layout col = lane&15, row = (lane>>4)*4 + reg
    const int crow0 = fc << 2;
#pragma unroll
    for (int m = 0; m < NFR; ++m) {
        const int row_b = am0 + wm * (BM / 2) + m * 16 + crow0;
#pragma unroll
        for (int n = 0; n < 4; ++n) {
            const int col = bn0 + wn * 64 + n * 16 + fr;
            const float bs = bias[col];
#pragma unroll
            for (int r = 0; r < 4; ++r) {
                const float v = acc[m][n][r] + bs;
                if (STORE_BF16)
                    ((ushort_t*)C)[(size_t)(row_b + r) * N + col] = f2bf(v);
                else
                    ((float*)C)[(size_t)(row_b + r) * N + col] = v;
            }
        }
    }
#undef QT
#undef SA0
#undef SA1
#undef SB0
#undef SB1
}

// ========== fused attention: rope+norm -> R-projection -> sin/cos ==========
// ========== -> A = qp.kp^T (MFMA) -> out = 2*A*v -> scrambled ctx ==========
__global__ __launch_bounds__(256) void fused_attn_kernel(
    const ushort_t* __restrict__ qkv, const ushort_t* __restrict__ Rbf,
    ushort_t* __restrict__ ctx)
{
    __shared__ ushort_t xnb[32][136];   // roped+normalized q(0-15),k(16-23); 24-31 junk
    __shared__ ushort_t fpb[32][136];   // feats [sin|cos]/sqrt(F); 24-31 junk
    __shared__ float vsm[8][132];
    __shared__ float Am[16][20];

    const int tok = blockIdx.x;
    const int b = tok >> 11, s = tok & 2047;
    const int tid = threadIdx.x;
    const int wid = tid >> 6, lane = tid & 63;
    const ushort_t* row = qkv + (size_t)tok * 4096;

    // --- stage A: rope + unit-normalize -> xnb; stage v -> vsm ---
    float invf = exp2f(-(float)lane * (13.287712379549449f / 64.0f));
    float ang = (float)s * invf;
    float sn, cs;
    __sincosf(ang, &sn, &cs);
#pragma unroll
    for (int i = 0; i < 6; ++i) {
        int vec = wid * 6 + i;
        int base = (vec < 16) ? vec * 128 : 2048 + (vec - 16) * 128;
        float a = bf2f(row[base + lane]);
        float c = bf2f(row[base + lane + 64]);
        float ra = a * cs - c * sn;
        float rc = c * cs + a * sn;
        float ss2 = ra * ra + rc * rc;
#pragma unroll
        for (int off = 32; off; off >>= 1) ss2 += __shfl_xor(ss2, off);
        float inv = 1.0f / fmaxf(sqrtf(ss2), 1e-6f);
        xnb[vec][lane]      = f2bf(ra * inv);
        xnb[vec][lane + 64] = f2bf(rc * inv);
    }
    for (int idx = tid; idx < 1024; idx += 256)
        vsm[idx >> 7][idx & 127] = bf2f(row[3072 + idx]);
    __syncthreads();

    // --- stage B: p = xn @ R^T via MFMA (wave w owns e-tile w), sin/cos -> fpb ---
    {
        const int fr = lane & 15, fc = lane >> 4;
        f32x4 pacc[2] = {};
#pragma unroll
        for (int kc = 0; kc < 4; ++kc) {
            bf16x8 bfrag = *reinterpret_cast<const bf16x8*>(
                Rbf + (wid * 16 + fr) * 128 + kc * 32 + fc * 8);
            bf16x8 a0 = *reinterpret_cast<const bf16x8*>(&xnb[fr][kc * 32 + fc * 8]);
            bf16x8 a1 = *reinterpret_cast<const bf16x8*>(&xnb[16 + fr][kc * 32 + fc * 8]);
            pacc[0] = __builtin_amdgcn_mfma_f32_16x16x32_bf16(a0, bfrag, pacc[0], 0, 0, 0);
            pacc[1] = __builtin_amdgcn_mfma_f32_16x16x32_bf16(a1, bfrag, pacc[1], 0, 0, 0);
        }
        const int e = wid * 16 + fr;
#pragma unroll
        for (int m = 0; m < 2; ++m) {
            if (m == 1 && fc >= 2) break;   // vec >= 24: junk, skip
#pragma unroll
            for (int r = 0; r < 4; ++r) {
                int vec = m * 16 + fc * 4 + r;
                float sp, cp;
                __sincosf(pacc[m][r], &sp, &cp);
                fpb[vec][e]      = f2bf(sp * 0.08838834764831845f);
                fpb[vec][e + 64] = f2bf(cp * 0.08838834764831845f);
            }
        }
    }
    __syncthreads();

    // --- stage C: Am[q][hk] = 2 * <qp[q], kp[hk]> via one-wave MFMA ---
    if (wid == 0) {
        const int fr = lane & 15, fc = lane >> 4;
        f32x4 aacc = {};
#pragma unroll
        for (int kc = 0; kc < 4; ++kc) {
            bf16x8 qa = *reinterpret_cast<const bf16x8*>(&fpb[fr][kc * 32 + fc * 8]);
            bf16x8 ka = *reinterpret_cast<const bf16x8*>(&fpb[16 + fr][kc * 32 + fc * 8]);
            aacc = __builtin_amdgcn_mfma_f32_16x16x32_bf16(qa, ka, aacc, 0, 0, 0);
        }
        if (fr < 8)   // cols 8-15 come from junk rows — discard
#pragma unroll
            for (int r = 0; r < 4; ++r)
                Am[fc * 4 + r][fr] = 2.0f * aacc[r];
    }
    __syncthreads();

    // --- stage D: out[h][d0..d0+3] = sum_hk Am[h][hk] * v[hk][d0..d0+3] ---
    for (int g = tid; g < 512; g += 256) {
        int h = g >> 5;
        int d0 = (g & 31) << 2;
        float4 a = make_float4(0.f, 0.f, 0.f, 0.f);
#pragma unroll
        for (int hk = 0; hk < 8; ++hk) {
            float am = Am[h][hk];
            float4 v = *reinterpret_cast<const float4*>(&vsm[hk][d0]);
            a.x = fmaf(am, v.x, a.x); a.y = fmaf(am, v.y, a.y);
            a.z = fmaf(am, v.z, a.z); a.w = fmaf(am, v.w, a.w);
        }
        int orow = (b << 11) + (h << 7) + (s >> 4);
        int ocol = ((s & 15) << 7) + d0;
        ushort4 o;
        o.x = f2bf(a.x); o.y = f2bf(a.y); o.z = f2bf(a.z); o.w = f2bf(a.w);
        *reinterpret_cast<ushort4*>(&ctx[(size_t)orow * 2048 + ocol]) = o;
    }
}

// ---------- launch ----------
extern "C" void kernel_launch(void* const* d_in, const int* in_sizes, int n_in,
                              void* d_out, int out_size, void* d_ws, size_t ws_size,
                              hipStream_t stream)
{
    const float* hs = (const float*)d_in[0];
    const float* Wq = (const float*)d_in[1];
    const float* bq = (const float*)d_in[2];
    const float* Wk = (const float*)d_in[3];
    const float* bk = (const float*)d_in[4];
    const float* Wv = (const float*)d_in[5];
    const float* bv = (const float*)d_in[6];
    const float* Wo = (const float*)d_in[7];
    const float* bo = (const float*)d_in[8];
    const float* Rm = (const float*)d_in[9];
    float* out = (float*)d_out;

    char* ws = (char*)d_ws;
    ushort_t* Xb   = (ushort_t*)(ws);                 // 4096x2048 bf16
    ushort_t* Wcat = (ushort_t*)(ws + 16777216);      // 4096x2048 bf16 (Wq;Wk;Wv)
    ushort_t* Wo16 = (ushort_t*)(ws + 33554432);      // 2048x2048 bf16
    ushort_t* qkv  = (ushort_t*)(ws + 41943040);      // 4096x4096 bf16
    ushort_t* ctx  = (ushort_t*)(ws + 75497472);      // 4096x2048 bf16 (scrambled)
    float*    bcat = (float*)   (ws + 92274688);      // 4096 f32
    ushort_t* Rbf  = (ushort_t*)(ws + 92291072);      // 64x128 bf16

    cast_all_kernel<<<10245, 256, 0, stream>>>(hs, Wq, Wk, Wv, Wo, Rm,
                                               bq, bk, bv,
                                               Xb, Wcat, Wo16, Rbf, bcat);

    // qkv = X @ [Wq;Wk;Wv]^T + bcat   (M=4096, N=4096, K=2048) — reg-pipelined
    gemm8r_kernel<256, 16, 16, 2048, true><<<256, 512, 0, stream>>>(
        Xb, Wcat, bcat, qkv, 4096, 4096);

    // fused rope+norm+feats+head-contraction -> scrambled ctx
    fused_attn_kernel<<<4096, 256, 0, stream>>>(qkv, Rbf, ctx);

    // out = ctx @ Wo^T + bo   (M=4096, N=2048, K=2048) — reg-pipelined
    gemm8r_kernel<128, 32, 8, 2048, false><<<256, 512, 0, stream>>>(
        ctx, Wo16, bo, out, 4096, 2048);
}

// Round 11
// 139.663 us; speedup vs baseline: 1.0081x; 1.0081x over previous
//
#include <hip/hip_runtime.h>
#include <stdint.h>

typedef unsigned short ushort_t;
typedef __bf16 bf16x8 __attribute__((ext_vector_type(8)));
typedef float f32x4 __attribute__((ext_vector_type(4)));
typedef unsigned int u32;

// ---------- bf16 helpers (manual, RNE) ----------
__device__ __forceinline__ float bf2f(ushort_t u) {
    union { u32 u; float f; } x; x.u = ((u32)u) << 16; return x.f;
}
__device__ __forceinline__ ushort_t f2bf(float f) {
    union { float f; u32 u; } x; x.f = f;
    u32 r = x.u + 0x7FFFu + ((x.u >> 16) & 1u);
    return (ushort_t)(r >> 16);
}

// ---------- async global->LDS, 16B per lane ----------
__device__ __forceinline__ void async16(const void* gp, void* lp) {
    __builtin_amdgcn_global_load_lds(
        (const __attribute__((address_space(1))) u32*)(gp),
        (__attribute__((address_space(3))) u32*)(lp),
        16, 0, 0);
}

template<int N>
__device__ __forceinline__ void wait_barrier() {
    asm volatile("s_waitcnt vmcnt(%0)\n\ts_barrier" :: "n"(N) : "memory");
}

// ---------- fused fp32 -> bf16 casts + bias concat (one launch) ----------
__global__ __launch_bounds__(256) void cast_all_kernel(
    const float* __restrict__ hs, const float* __restrict__ Wq,
    const float* __restrict__ Wk, const float* __restrict__ Wv,
    const float* __restrict__ Wo, const float* __restrict__ Rm,
    const float* __restrict__ bq, const float* __restrict__ bk,
    const float* __restrict__ bv,
    ushort_t* __restrict__ Xb, ushort_t* __restrict__ Wcat,
    ushort_t* __restrict__ Wo16, ushort_t* __restrict__ Rbf,
    float* __restrict__ bcat)
{
    int bid = blockIdx.x;
    if (bid == 10244) {   // concatenated qkv bias
        for (int i = threadIdx.x; i < 4096; i += 256) {
            float v = (i < 2048) ? bq[i] : (i < 3072) ? bk[i - 2048] : bv[i - 3072];
            bcat[i] = v;
        }
        return;
    }
    const float* src; ushort_t* dst; int base;
    if (bid < 4096)       { src = hs; dst = Xb;              base = bid; }
    else if (bid < 6144)  { src = Wq; dst = Wcat;            base = bid - 4096; }
    else if (bid < 7168)  { src = Wk; dst = Wcat + 4194304;  base = bid - 6144; }
    else if (bid < 8192)  { src = Wv; dst = Wcat + 6291456;  base = bid - 7168; }
    else if (bid < 10240) { src = Wo; dst = Wo16;            base = bid - 8192; }
    else                  { src = Rm; dst = Rbf;             base = bid - 10240; }
    int i = base * 2048 + threadIdx.x * 8;
    float4 v0 = *reinterpret_cast<const float4*>(src + i);
    float4 v1 = *reinterpret_cast<const float4*>(src + i + 4);
    ushort_t o[8];
    o[0] = f2bf(v0.x); o[1] = f2bf(v0.y); o[2] = f2bf(v0.z); o[3] = f2bf(v0.w);
    o[4] = f2bf(v1.x); o[5] = f2bf(v1.y); o[6] = f2bf(v1.z); o[7] = f2bf(v1.w);
    *reinterpret_cast<uint4*>(dst + i) = *reinterpret_cast<const uint4*>(o);
}

#define CLOSE_PLAIN __builtin_amdgcn_s_barrier()
#define CLOSE_VM(nn) do { asm volatile("s_waitcnt vmcnt(%0)" :: "n"(nn) : "memory"); \
                          __builtin_amdgcn_s_barrier(); } while (0)
#define SBAR __builtin_amdgcn_sched_barrier(0)

// ============ gemm8r: reg-pipelined variant (best for BM=256 / GEMM1) ============
template<int BM, int MBLK, int NBLK, int KC, bool STORE_BF16>
__global__ __launch_bounds__(512, 2) void gemm8r_kernel(
    const ushort_t* __restrict__ A, const ushort_t* __restrict__ B,
    const float* __restrict__ bias, void* __restrict__ C,
    const int M, const int N)
{
    constexpr int NT  = KC / 64;
    constexpr int NI  = NT / 2;
    constexpr int MF2 = BM / 64;
    constexpr int NFR = BM / 32;
    constexpr int AH  = BM * 64;
    constexpr int SH  = BM / 128;
    constexpr int BUF = 2 * AH + 32768;
    constexpr int TI  = 2 * SH + 4;
    static_assert(NT % 2 == 0 && NI >= 3, "need even NT >= 6");
    __shared__ alignas(16) char lds[2 * BUF];

    const int tid  = threadIdx.x;
    const int wid  = tid >> 6;
    const int lane = tid & 63;
    const int wm = wid >> 2, wn = wid & 3;

    constexpr int XN  = NBLK / 8;
    constexpr int NXR = 8 / XN;
    constexpr int RH  = MBLK / NXR;
    const int x  = blockIdx.x & 7;
    const int kb = blockIdx.x >> 3;
    const int mb = (x % NXR) * RH + (kb >> 3);
    const int nb = (x / NXR) * 8 + (kb & 7);
    const int am0 = mb * BM, bn0 = nb * 256;

    const int sr3 = tid >> 3;
    const int c8  = tid & 7;
    const int cs  = c8 ^ (sr3 & 7);
    const long K2 = (long)KC * 2;
    const char* agp = (const char*)A + (size_t)(am0 + sr3) * K2 + cs * 16;
    const char* bgp = (const char*)B + (size_t)(bn0 + sr3) * K2 + cs * 16;
    const int ldsw = wid << 10;

    const int fr = lane & 15, fc = lane >> 4;
    const int sw0 = ((fc)     ^ (fr & 7)) * 16;
    const int sw1 = ((4 + fc) ^ (fr & 7)) * 16;
    const int abase = wm * AH + fr * 128;
    const int bbase = 2 * AH + wn * 8192 + fr * 128;

    f32x4 acc[NFR][4] = {};
    bf16x8 afX[MF2], afY[MF2], bfX[4], bfY[4];

    auto stage_half = [&](const char* gp, int rowoff, int bufb, int off,
                          long kof, int niss) {
        char* lp = lds + bufb + off + ldsw;
        const char* g = gp + (size_t)rowoff * K2 + kof;
#pragma unroll
        for (int i = 0; i < niss; ++i)
            async16(g + (size_t)(i * 64) * K2, lp + i * 8192);
    };
#define SA0(T) stage_half(agp, 0,      ((T) & 1) * BUF, 0,          (long)(T) * 128, SH)
#define SA1(T) stage_half(agp, BM / 2, ((T) & 1) * BUF, AH,         (long)(T) * 128, SH)
#define SB0(T) stage_half(bgp, 0,      ((T) & 1) * BUF, 2 * AH,     (long)(T) * 128, 2)
#define SB1(T) stage_half(bgp, 128,    ((T) & 1) * BUF, 2 * AH + 16384, (long)(T) * 128, 2)

    auto rdA = [&](bf16x8 (&dst)[MF2], int bufb, int h, int kc) {
        const char* lp_ = lds + bufb;
        const int sw_ = kc ? sw1 : sw0;
#pragma unroll
        for (int j = 0; j < MF2; ++j)
            dst[j] = *(const bf16x8*)(lp_ + abase + (h * MF2 + j) * 2048 + sw_);
    };
    auto rdB = [&](bf16x8 (&dst)[4], int bufb, int kc) {
        const char* lp_ = lds + bufb;
        const int sw_ = kc ? sw1 : sw0;
#pragma unroll
        for (int n = 0; n < 4; ++n)
            dst[n] = *(const bf16x8*)(lp_ + bbase + n * 2048 + sw_);
    };
    auto domf = [&](bf16x8 (&af)[MF2], bf16x8 (&bf)[4], int h) {
        __builtin_amdgcn_s_setprio(1);
#pragma unroll
        for (int j = 0; j < MF2; ++j)
#pragma unroll
            for (int n = 0; n < 4; ++n)
                acc[h * MF2 + j][n] = __builtin_amdgcn_mfma_f32_16x16x32_bf16(
                    af[j], bf[n], acc[h * MF2 + j][n], 0, 0, 0);
        __builtin_amdgcn_s_setprio(0);
    };

#define QT(b, S0, C0, S1, C1, S2, C2, S3, C3) do {                 \
    rdA(afX, b, 0, 0); rdB(bfX, b, 0); rdA(afY, b, 1, 0);          \
    S0; SBAR; domf(afX, bfX, 0); C0;                               \
    rdA(afX, b, 0, 1); rdB(bfY, b, 1);                             \
    S1; SBAR; domf(afY, bfX, 1); C1;                               \
    rdA(afY, b, 1, 1);                                             \
    S2; SBAR; domf(afX, bfY, 0); C2;                               \
    S3; SBAR; domf(afY, bfY, 1); C3;                               \
} while (0)

    SA0(0); SA1(0); SB0(0); SB1(0);
    SA0(1); SA1(1); SB0(1); SB1(1);
    wait_barrier<TI>();

    QT(0,   (void)0, CLOSE_PLAIN, (void)0, CLOSE_PLAIN,
            (void)0, CLOSE_PLAIN, SB0(2),  CLOSE_VM(2));
    QT(BUF, SB1(2),  CLOSE_PLAIN, SA0(2),  CLOSE_PLAIN,
            SA1(2),  CLOSE_PLAIN, SB0(3),  CLOSE_VM(2));

    for (int i = 1; i <= NI - 2; ++i) {
        const int t = 2 * i;
        QT(0,   SB1(t + 1), CLOSE_PLAIN, SA0(t + 1), CLOSE_PLAIN,
                SA1(t + 1), CLOSE_PLAIN, SB0(t + 2), CLOSE_VM(2));
        QT(BUF, SB1(t + 2), CLOSE_PLAIN, SA0(t + 2), CLOSE_PLAIN,
                SA1(t + 2), CLOSE_PLAIN, SB0(t + 3), CLOSE_VM(2));
    }

    {
        constexpr int T1 = NT - 1;
        QT(0,   SB1(T1), CLOSE_PLAIN, SA0(T1), CLOSE_PLAIN,
                SA1(T1), CLOSE_PLAIN, (void)0, CLOSE_VM(0));
        QT(BUF, (void)0, CLOSE_PLAIN, (void)0, CLOSE_PLAIN,
                (void)0, CLOSE_PLAIN, (void)0, CLOSE_PLAIN);
    }

    const int crow0 = fc << 2;
#pragma unroll
    for (int m = 0; m < NFR; ++m) {
        const int row_b = am0 + wm * (BM / 2) + m * 16 + crow0;
#pragma unroll
        for (int n = 0; n < 4; ++n) {
            const int col = bn0 + wn * 64 + n * 16 + fr;
            const float bs = bias[col];
#pragma unroll
            for (int r = 0; r < 4; ++r) {
                const float v = acc[m][n][r] + bs;
                if (STORE_BF16)
                    ((ushort_t*)C)[(size_t)(row_b + r) * N + col] = f2bf(v);
                else
                    ((float*)C)[(size_t)(row_b + r) * N + col] = v;
            }
        }
    }
#undef QT
#undef SA0
#undef SA1
#undef SB0
#undef SB1
}

// ============ gemm8p: read-own variant (best for BM=128 / GEMM2) ============
template<int BM, int MBLK, int NBLK, int KC, bool STORE_BF16>
__global__ __launch_bounds__(512, 2) void gemm8p_kernel(
    const ushort_t* __restrict__ A, const ushort_t* __restrict__ B,
    const float* __restrict__ bias, void* __restrict__ C,
    const int M, const int N)
{
    constexpr int NT  = KC / 64;
    constexpr int NI  = NT / 2;
    constexpr int MF2 = BM / 64;
    constexpr int NFR = BM / 32;
    constexpr int AH  = BM * 64;
    constexpr int SH  = BM / 128;
    constexpr int BUF = 2 * AH + 32768;
    constexpr int TI  = 2 * SH + 4;
    static_assert(NT % 2 == 0 && NI >= 3, "need even NT >= 6");
    __shared__ alignas(16) char lds[2 * BUF];

    const int tid  = threadIdx.x;
    const int wid  = tid >> 6;
    const int lane = tid & 63;
    const int wm = wid >> 2, wn = wid & 3;

    constexpr int XN  = NBLK / 8;
    constexpr int NXR = 8 / XN;
    constexpr int RH  = MBLK / NXR;
    const int x  = blockIdx.x & 7;
    const int kb = blockIdx.x >> 3;
    const int mb = (x % NXR) * RH + (kb >> 3);
    const int nb = (x / NXR) * 8 + (kb & 7);
    const int am0 = mb * BM, bn0 = nb * 256;

    const int sr3 = tid >> 3;
    const int c8  = tid & 7;
    const int cs  = c8 ^ (sr3 & 7);
    const long K2 = (long)KC * 2;
    const char* agp = (const char*)A + (size_t)(am0 + sr3) * K2 + cs * 16;
    const char* bgp = (const char*)B + (size_t)(bn0 + sr3) * K2 + cs * 16;
    const int ldsw = wid << 10;

    const int fr = lane & 15, fc = lane >> 4;
    const int sw0 = ((fc)     ^ (fr & 7)) * 16;
    const int sw1 = ((4 + fc) ^ (fr & 7)) * 16;
    const int abase = wm * AH + fr * 128;
    const int bbase = 2 * AH + wn * 8192 + fr * 128;

    f32x4 acc[NFR][4] = {};
    bf16x8 bf[4];

    auto stage_half = [&](const char* gp, int rowoff, int bufb, int off,
                          long kof, int niss) {
        char* lp = lds + bufb + off + ldsw;
        const char* g = gp + (size_t)rowoff * K2 + kof;
#pragma unroll
        for (int i = 0; i < niss; ++i)
            async16(g + (size_t)(i * 64) * K2, lp + i * 8192);
    };
#define SA0(T) stage_half(agp, 0,      ((T) & 1) * BUF, 0,          (long)(T) * 128, SH)
#define SA1(T) stage_half(agp, BM / 2, ((T) & 1) * BUF, AH,         (long)(T) * 128, SH)
#define SB0(T) stage_half(bgp, 0,      ((T) & 1) * BUF, 2 * AH,     (long)(T) * 128, 2)
#define SB1(T) stage_half(bgp, 128,    ((T) & 1) * BUF, 2 * AH + 16384, (long)(T) * 128, 2)

#define PH(h, kc, bufb, STG, CLOSE) do {                                      \
    const char* lp_ = lds + (bufb);                                           \
    const int sw_ = (kc) ? sw1 : sw0;                                         \
    if ((h) == 0) {                                                           \
        _Pragma("unroll") for (int n = 0; n < 4; ++n)                         \
            bf[n] = *(const bf16x8*)(lp_ + bbase + n * 2048 + sw_);           \
    }                                                                         \
    bf16x8 af_[MF2];                                                          \
    _Pragma("unroll") for (int j = 0; j < MF2; ++j)                           \
        af_[j] = *(const bf16x8*)(lp_ + abase + ((h) * MF2 + j) * 2048 + sw_);\
    STG;                                                                      \
    __builtin_amdgcn_s_barrier();                                             \
    asm volatile("s_waitcnt lgkmcnt(0)" ::: "memory");                        \
    __builtin_amdgcn_s_setprio(1);                                            \
    _Pragma("unroll") for (int j = 0; j < MF2; ++j)                           \
    _Pragma("unroll") for (int n = 0; n < 4; ++n)                             \
        acc[(h) * MF2 + j][n] = __builtin_amdgcn_mfma_f32_16x16x32_bf16(      \
            af_[j], bf[n], acc[(h) * MF2 + j][n], 0, 0, 0);                   \
    __builtin_amdgcn_s_setprio(0);                                            \
    CLOSE;                                                                    \
} while (0)

    SA0(0); SA1(0); SB0(0); SB1(0);
    SA0(1); SA1(1); SB0(1); SB1(1);
    wait_barrier<TI>();

    PH(0, 0, 0,    (void)0,  CLOSE_PLAIN);
    PH(1, 0, 0,    (void)0,  CLOSE_PLAIN);
    PH(0, 1, 0,    (void)0,  CLOSE_PLAIN);
    PH(1, 1, 0,    SB0(2),   CLOSE_VM(2));
    PH(0, 0, BUF,  SB1(2),   CLOSE_PLAIN);
    PH(1, 0, BUF,  SA0(2),   CLOSE_PLAIN);
    PH(0, 1, BUF,  SA1(2),   CLOSE_PLAIN);
    PH(1, 1, BUF,  SB0(3),   CLOSE_VM(2));

    for (int i = 1; i <= NI - 2; ++i) {
        const int t = 2 * i;
        PH(0, 0, 0,    SB1(t + 1), CLOSE_PLAIN);
        PH(1, 0, 0,    SA0(t + 1), CLOSE_PLAIN);
        PH(0, 1, 0,    SA1(t + 1), CLOSE_PLAIN);
        PH(1, 1, 0,    SB0(t + 2), CLOSE_VM(2));
        PH(0, 0, BUF,  SB1(t + 2), CLOSE_PLAIN);
        PH(1, 0, BUF,  SA0(t + 2), CLOSE_PLAIN);
        PH(0, 1, BUF,  SA1(t + 2), CLOSE_PLAIN);
        PH(1, 1, BUF,  SB0(t + 3), CLOSE_VM(2));
    }

    {
        constexpr int T1 = NT - 1;
        PH(0, 0, 0,    SB1(T1),  CLOSE_PLAIN);
        PH(1, 0, 0,    SA0(T1),  CLOSE_PLAIN);
        PH(0, 1, 0,    SA1(T1),  CLOSE_PLAIN);
        PH(1, 1, 0,    (void)0,  CLOSE_VM(0));
        PH(0, 0, BUF,  (void)0,  CLOSE_PLAIN);
        PH(1, 0, BUF,  (void)0,  CLOSE_PLAIN);
        PH(0, 1, BUF,  (void)0,  CLOSE_PLAIN);
        PH(1, 1, BUF,  (void)0,  CLOSE_PLAIN);
    }

    const int crow0 = fc << 2;
#pragma unroll
    for (int m = 0; m < NFR; ++m) {
        const int row_b = am0 + wm * (BM / 2) + m * 16 + crow0;
#pragma unroll
        for (int n = 0; n < 4; ++n) {
            const int col = bn0 + wn * 64 + n * 16 + fr;
            const float bs = bias[col];
#pragma unroll
            for (int r = 0; r < 4; ++r) {
                const float v = acc[m][n][r] + bs;
                if (STORE_BF16)
                    ((ushort_t*)C)[(size_t)(row_b + r) * N + col] = f2bf(v);
                else
                    ((float*)C)[(size_t)(row_b + r) * N + col] = v;
            }
        }
    }
#undef PH
#undef SA0
#undef SA1
#undef SB0
#undef SB1
}

// ========== fused attention: rope+norm -> R-projection -> sin/cos ==========
// ========== -> A = qp.kp^T (MFMA) -> out = 2*A*v -> scrambled ctx ==========
__global__ __launch_bounds__(256) void fused_attn_kernel(
    const ushort_t* __restrict__ qkv, const ushort_t* __restrict__ Rbf,
    ushort_t* __restrict__ ctx)
{
    __shared__ ushort_t xnb[32][136];   // roped+normalized q(0-15),k(16-23); 24-31 junk
    __shared__ ushort_t fpb[32][136];   // feats [sin|cos]/sqrt(F); 24-31 junk
    __shared__ float vsm[8][132];
    __shared__ float Am[16][20];

    const int tok = blockIdx.x;
    const int b = tok >> 11, s = tok & 2047;
    const int tid = threadIdx.x;
    const int wid = tid >> 6, lane = tid & 63;
    const ushort_t* row = qkv + (size_t)tok * 4096;

    float invf = exp2f(-(float)lane * (13.287712379549449f / 64.0f));
    float ang = (float)s * invf;
    float sn, cs;
    __sincosf(ang, &sn, &cs);
#pragma unroll
    for (int i = 0; i < 6; ++i) {
        int vec = wid * 6 + i;
        int base = (vec < 16) ? vec * 128 : 2048 + (vec - 16) * 128;
        float a = bf2f(row[base + lane]);
        float c = bf2f(row[base + lane + 64]);
        float ra = a * cs - c * sn;
        float rc = c * cs + a * sn;
        float ss2 = ra * ra + rc * rc;
#pragma unroll
        for (int off = 32; off; off >>= 1) ss2 += __shfl_xor(ss2, off);
        float inv = 1.0f / fmaxf(sqrtf(ss2), 1e-6f);
        xnb[vec][lane]      = f2bf(ra * inv);
        xnb[vec][lane + 64] = f2bf(rc * inv);
    }
    for (int idx = tid; idx < 1024; idx += 256)
        vsm[idx >> 7][idx & 127] = bf2f(row[3072 + idx]);
    __syncthreads();

    {
        const int fr = lane & 15, fc = lane >> 4;
        f32x4 pacc[2] = {};
#pragma unroll
        for (int kc = 0; kc < 4; ++kc) {
            bf16x8 bfrag = *reinterpret_cast<const bf16x8*>(
                Rbf + (wid * 16 + fr) * 128 + kc * 32 + fc * 8);
            bf16x8 a0 = *reinterpret_cast<const bf16x8*>(&xnb[fr][kc * 32 + fc * 8]);
            bf16x8 a1 = *reinterpret_cast<const bf16x8*>(&xnb[16 + fr][kc * 32 + fc * 8]);
            pacc[0] = __builtin_amdgcn_mfma_f32_16x16x32_bf16(a0, bfrag, pacc[0], 0, 0, 0);
            pacc[1] = __builtin_amdgcn_mfma_f32_16x16x32_bf16(a1, bfrag, pacc[1], 0, 0, 0);
        }
        const int e = wid * 16 + fr;
#pragma unroll
        for (int m = 0; m < 2; ++m) {
            if (m == 1 && fc >= 2) break;   // vec >= 24: junk, skip
#pragma unroll
            for (int r = 0; r < 4; ++r) {
                int vec = m * 16 + fc * 4 + r;
                float sp, cp;
                __sincosf(pacc[m][r], &sp, &cp);
                fpb[vec][e]      = f2bf(sp * 0.08838834764831845f);
                fpb[vec][e + 64] = f2bf(cp * 0.08838834764831845f);
            }
        }
    }
    __syncthreads();

    if (wid == 0) {
        const int fr = lane & 15, fc = lane >> 4;
        f32x4 aacc = {};
#pragma unroll
        for (int kc = 0; kc < 4; ++kc) {
            bf16x8 qa = *reinterpret_cast<const bf16x8*>(&fpb[fr][kc * 32 + fc * 8]);
            bf16x8 ka = *reinterpret_cast<const bf16x8*>(&fpb[16 + fr][kc * 32 + fc * 8]);
            aacc = __builtin_amdgcn_mfma_f32_16x16x32_bf16(qa, ka, aacc, 0, 0, 0);
        }
        if (fr < 8)
#pragma unroll
            for (int r = 0; r < 4; ++r)
                Am[fc * 4 + r][fr] = 2.0f * aacc[r];
    }
    __syncthreads();

    for (int g = tid; g < 512; g += 256) {
        int h = g >> 5;
        int d0 = (g & 31) << 2;
        float4 a = make_float4(0.f, 0.f, 0.f, 0.f);
#pragma unroll
        for (int hk = 0; hk < 8; ++hk) {
            float am = Am[h][hk];
            float4 v = *reinterpret_cast<const float4*>(&vsm[hk][d0]);
            a.x = fmaf(am, v.x, a.x); a.y = fmaf(am, v.y, a.y);
            a.z = fmaf(am, v.z, a.z); a.w = fmaf(am, v.w, a.w);
        }
        int orow = (b << 11) + (h << 7) + (s >> 4);
        int ocol = ((s & 15) << 7) + d0;
        ushort4 o;
        o.x = f2bf(a.x); o.y = f2bf(a.y); o.z = f2bf(a.z); o.w = f2bf(a.w);
        *reinterpret_cast<ushort4*>(&ctx[(size_t)orow * 2048 + ocol]) = o;
    }
}

// ---------- launch ----------
extern "C" void kernel_launch(void* const* d_in, const int* in_sizes, int n_in,
                              void* d_out, int out_size, void* d_ws, size_t ws_size,
                              hipStream_t stream)
{
    const float* hs = (const float*)d_in[0];
    const float* Wq = (const float*)d_in[1];
    const float* bq = (const float*)d_in[2];
    const float* Wk = (const float*)d_in[3];
    const float* bk = (const float*)d_in[4];
    const float* Wv = (const float*)d_in[5];
    const float* bv = (const float*)d_in[6];
    const float* Wo = (const float*)d_in[7];
    const float* bo = (const float*)d_in[8];
    const float* Rm = (const float*)d_in[9];
    float* out = (float*)d_out;

    char* ws = (char*)d_ws;
    ushort_t* Xb   = (ushort_t*)(ws);                 // 4096x2048 bf16
    ushort_t* Wcat = (ushort_t*)(ws + 16777216);      // 4096x2048 bf16 (Wq;Wk;Wv)
    ushort_t* Wo16 = (ushort_t*)(ws + 33554432);      // 2048x2048 bf16
    ushort_t* qkv  = (ushort_t*)(ws + 41943040);      // 4096x4096 bf16
    ushort_t* ctx  = (ushort_t*)(ws + 75497472);      // 4096x2048 bf16 (scrambled)
    float*    bcat = (float*)   (ws + 92274688);      // 4096 f32
    ushort_t* Rbf  = (ushort_t*)(ws + 92291072);      // 64x128 bf16

    cast_all_kernel<<<10245, 256, 0, stream>>>(hs, Wq, Wk, Wv, Wo, Rm,
                                               bq, bk, bv,
                                               Xb, Wcat, Wo16, Rbf, bcat);

    // qkv = X @ [Wq;Wk;Wv]^T + bcat   (M=4096, N=4096, K=2048) — gemm8r (best)
    gemm8r_kernel<256, 16, 16, 2048, true><<<256, 512, 0, stream>>>(
        Xb, Wcat, bcat, qkv, 4096, 4096);

    // fused rope+norm+feats+head-contraction -> scrambled ctx
    fused_attn_kernel<<<4096, 256, 0, stream>>>(qkv, Rbf, ctx);

    // out = ctx @ Wo^T + bo   (M=4096, N=2048, K=2048) — gemm8p (best at BM=128)
    gemm8p_kernel<128, 32, 8, 2048, false><<<256, 512, 0, stream>>>(
        ctx, Wo16, bo, out, 4096, 2048);
}